// Round 8
// baseline (1393.310 us; speedup 1.0000x reference)
//
#include <hip/hip_runtime.h>

// Locally connected layer:
// out[b,o,h,w] = sum_{c,i,j} x[b,c,h+i,w+j] * W[o,c,h,w,i,j] + bias[o,h,w]
// x: [32,32,64,64] f32, W: [64,32,62,62,3,3] f32, bias: [64,62,62] f32
// out: [32,64,62,62] f32
//
// R8 = R7 with the DPP direction fixed: row_shl:1 (0x101) gives
// dst[i] = src[i+1]  (row_shr:1/0x111 was src[i-1] -> wrong-neighbor data).
//  - x staged in LDS (gll dwordx4, double-buffered, 2x24KB) shared by 4 waves.
//  - x LDS reads: ONE ds_read_b128 per (bi,row); cols w0+4/w0+5 via DPP
//    row_shl:1 from lane wg+1 (VALU pipe, not LDS). 24 reads/wave/c.
//  - W: direct global float2 x18, double-buffered wvA/wvB.
//  - launch_bounds(256,3): 3 blocks/CU, VGPR cap 170.

#define C_  32
#define B_  32
#define O_  64
#define H_  64
#define W_  64
#define OH_ 62
#define OW_ 62

typedef float vfloat2 __attribute__((ext_vector_type(2)));

#define GLL16(gaddr, laddr)                                                     \
    __builtin_amdgcn_global_load_lds(                                           \
        (const __attribute__((address_space(1))) void*)(gaddr),                 \
        (__attribute__((address_space(3))) void*)(laddr), 16, 0, 0)

// dst[lane] = src[lane+1] within each 16-lane row (last lane of row -> 0,
// unused: wg=15 is the non-full lane). DPP ROW_SHL1 = 0x101.
__device__ __forceinline__ float dpp_nextlane(float v) {
    return __int_as_float(__builtin_amdgcn_update_dpp(
        0, __float_as_int(v), 0x101, 0xf, 0xf, true));
}

__global__ __launch_bounds__(256, 3)
void lcl_kernel(const float* __restrict__ x,
                const float* __restrict__ Wt,
                const float* __restrict__ bias,
                float* __restrict__ out) {
    // x slab per channel: [batch 32][row 3][col 64] f32 = 24576 B, linear.
    __shared__ float lds[2][6144];

    // ---- chunked XCD swizzle (hw: XCD = blockIdx.x % 8)
    const int nblk    = (O_ / 4) * OH_;              // 992 = 8 * 124
    const int i0      = blockIdx.x;
    const int logical = (i0 & 7) * (nblk >> 3) + (i0 >> 3);
    const int og      = logical & 15;                // o-group (fast)
    const int h       = logical >> 4;                // 0..61

    const int wv_i = threadIdx.x >> 6;               // wave 0..3
    const int o    = (og << 2) + wv_i;
    const int lane = threadIdx.x & 63;
    const int wg   = lane & 15;                      // w0 = 4*wg
    const int bg   = lane >> 4;                      // b0 = 8*bg
    const int w0   = wg * 4;
    const int b0   = bg * 8;
    const bool full = (wg < 15);                     // wg15 -> only w=60,61 stored

    // ---- per-lane global source offsets for the 6 x-gll instrs (const in c)
    // slab byte S -> batch = S/768, within = S%768;
    // global byte = batch*524288 + h*256 + within (+ c*16384 per call)
    unsigned goff[6];
#pragma unroll
    for (int k = 0; k < 6; ++k) {
        unsigned S      = (unsigned)wv_i * 6144u + (unsigned)k * 1024u + (unsigned)lane * 16u;
        unsigned batch  = ((S >> 8) * 171u) >> 9;    // /768 for S<24576
        unsigned within = S - batch * 768u;
        goff[k] = batch * 524288u + (unsigned)h * 256u + within;
    }

    float acc[8][4];
#pragma unroll
    for (int bi = 0; bi < 8; ++bi)
#pragma unroll
        for (int wi = 0; wi < 4; ++wi) acc[bi][wi] = 0.f;

    // W flat idx = o*(C*OH*OW*9) + c*(OH*OW*9) + h*(OW*9) + w*9 + i*3 + j
    const long wcstride = (long)OH_ * OW_ * 9;       // 34596
    const long wbase0   = (long)o * C_ * wcstride + (long)h * (OW_ * 9) + (long)w0 * 9;

#define STAGE(bufptr, cidx) do {                                                \
        const char* xb_ = (const char*)x + (unsigned)(cidx) * 16384u;           \
        char* lb_ = (char*)(bufptr) + wv_i * 6144;                              \
        _Pragma("unroll")                                                       \
        for (int k_ = 0; k_ < 6; ++k_)                                          \
            GLL16(xb_ + goff[k_], lb_ + k_ * 1024);                             \
    } while (0)

#define LOADW(arr, cidx) do {                                                   \
        const float* wp_ = Wt + wbase0 + (long)(cidx) * wcstride;               \
        _Pragma("unroll")                                                       \
        for (int q_ = 0; q_ < 18; ++q_) {                                       \
            if (q_ < 9 || full) {                                               \
                vfloat2 v_ = *reinterpret_cast<const vfloat2*>(wp_ + 2 * q_);   \
                arr[2 * q_] = v_.x; arr[2 * q_ + 1] = v_.y;                     \
            } else { arr[2 * q_] = 0.f; arr[2 * q_ + 1] = 0.f; }                \
        }                                                                       \
    } while (0)

    // per (bi,row): one ds_read_b128 (cols w0..w0+3) + 2 DPP for w0+4, w0+5
#define COMPUTE(bufptr, warr) do {                                              \
        const char* bb_ = (const char*)(bufptr) + b0 * 768 + wg * 16;           \
        _Pragma("unroll")                                                       \
        for (int bi_ = 0; bi_ < 8; ++bi_) {                                     \
            float xr_[3][6];                                                    \
            _Pragma("unroll")                                                   \
            for (int r_ = 0; r_ < 3; ++r_) {                                    \
                float4 v4_ = *reinterpret_cast<const float4*>(                  \
                    bb_ + bi_ * 768 + r_ * 256);                                \
                xr_[r_][0] = v4_.x; xr_[r_][1] = v4_.y;                         \
                xr_[r_][2] = v4_.z; xr_[r_][3] = v4_.w;                         \
                xr_[r_][4] = dpp_nextlane(v4_.x);                               \
                xr_[r_][5] = dpp_nextlane(v4_.y);                               \
            }                                                                   \
            _Pragma("unroll")                                                   \
            for (int wi_ = 0; wi_ < 4; ++wi_)                                   \
            _Pragma("unroll")                                                   \
            for (int ii_ = 0; ii_ < 3; ++ii_)                                   \
            _Pragma("unroll")                                                   \
            for (int j_ = 0; j_ < 3; ++j_)                                      \
                acc[bi_][wi_] = fmaf(xr_[ii_][wi_ + j_],                        \
                                     warr[wi_ * 9 + ii_ * 3 + j_],              \
                                     acc[bi_][wi_]);                            \
        }                                                                       \
    } while (0)

    float wvA[36], wvB[36];

    // ---- prologue
    STAGE(lds[0], 0);
    LOADW(wvA, 0);
    __syncthreads();                 // drains gll(0)

    // ---- main loop, 2 channels per iteration (static wvA/wvB alternation)
    for (int cc = 0; cc < C_; cc += 2) {
        STAGE(lds[1], cc + 1);
        LOADW(wvB, cc + 1);
        COMPUTE(lds[0], wvA);
        __syncthreads();

        if (cc + 2 < C_) {
            STAGE(lds[0], cc + 2);
            LOADW(wvA, cc + 2);
        }
        COMPUTE(lds[1], wvB);
        __syncthreads();
    }

    // ---- epilogue: bias + nontemporal float2 stores (8B-aligned)
    const float* brow = bias + ((long)o * OH_ + h) * OW_ + w0;
    float2 bv0 = *reinterpret_cast<const float2*>(brow);
    float2 bv1;
    if (full) bv1 = *reinterpret_cast<const float2*>(brow + 2);
    else { bv1.x = 0.f; bv1.y = 0.f; }

#pragma unroll
    for (int bi = 0; bi < 8; ++bi) {
        float* orow = out + (((long)(b0 + bi) * O_ + o) * OH_ + h) * OW_ + w0;
        vfloat2 s0; s0.x = acc[bi][0] + bv0.x; s0.y = acc[bi][1] + bv0.y;
        __builtin_nontemporal_store(s0, reinterpret_cast<vfloat2*>(orow));
        if (full) {
            vfloat2 s1; s1.x = acc[bi][2] + bv1.x; s1.y = acc[bi][3] + bv1.y;
            __builtin_nontemporal_store(s1, reinterpret_cast<vfloat2*>(orow) + 1);
        }
    }

#undef STAGE
#undef LOADW
#undef COMPUTE
}

extern "C" void kernel_launch(void* const* d_in, const int* in_sizes, int n_in,
                              void* d_out, int out_size, void* d_ws, size_t ws_size,
                              hipStream_t stream) {
    const float* x    = (const float*)d_in[0];
    const float* Wt   = (const float*)d_in[1];
    const float* bias = (const float*)d_in[2];
    float* out        = (float*)d_out;

    dim3 grid((O_ / 4) * OH_);   // 992 blocks, XCD-swizzled in-kernel
    dim3 block(256);
    lcl_kernel<<<grid, block, 0, stream>>>(x, Wt, bias, out);
}

// Round 9
// 353.365 us; speedup vs baseline: 3.9430x; 3.9430x over previous
//
#include <hip/hip_runtime.h>

// Locally connected layer:
// out[b,o,h,w] = sum_{c,i,j} x[b,c,h+i,w+j] * W[o,c,h,w,i,j] + bias[o,h,w]
// x: [32,32,64,64] f32, W: [64,32,62,62,3,3] f32, bias: [64,62,62] f32
// out: [32,64,62,62] f32
//
// R9: barrier-free direct-load structure.
//  - NO LDS (R6/R8 analysis: 288 ds_read_b128/CU/c-step ~ 3400 cy on the
//    shared LDS pipe vs 1728 cy FMA/SIMD -> LDS was the oversubscribed pipe;
//    x is L2-resident anyway with the chunked XCD swizzle). No barriers ->
//    waves free-run and stagger, hiding latency.
//  - x: one float4 per (bi,row) direct from global; halo cols w0+4/w0+5 via
//    DPP 0x101 from lane wg+1 (validated R8, absmax 0.25). 24 loads/wave/c.
//  - W: per-lane 18 float2, double-buffered wvA/wvB, prefetched one full
//    channel ahead (~660 cy of compute covers the ~900 cy HBM latency with
//    wave interleave).
//  - __launch_bounds__(256) ONLY: min-waves clauses spilled in R4 (VGPR 64,
//    6 GB scratch) and R8 (VGPR 84, 3 GB scratch). Never again.
//  - Chunked XCD swizzle kept (validated: FETCH 546->334 MB).

#define C_  32
#define B_  32
#define O_  64
#define H_  64
#define W_  64
#define OH_ 62
#define OW_ 62

typedef float vfloat2 __attribute__((ext_vector_type(2)));

// dst[lane] = src[lane+1] within each 16-lane row; last lane of row -> 0
// (unused: wg=15 stores only w=60,61). Empirically validated in R8.
__device__ __forceinline__ float dpp_nextlane(float v) {
    return __int_as_float(__builtin_amdgcn_update_dpp(
        0, __float_as_int(v), 0x101, 0xf, 0xf, true));
}

__global__ __launch_bounds__(256)
void lcl_kernel(const float* __restrict__ x,
                const float* __restrict__ Wt,
                const float* __restrict__ bias,
                float* __restrict__ out) {
    // ---- chunked XCD swizzle (hw: XCD = blockIdx.x % 8)
    const int nblk    = (O_ / 4) * OH_;              // 992 = 8 * 124
    const int i0      = blockIdx.x;
    const int logical = (i0 & 7) * (nblk >> 3) + (i0 >> 3);
    const int og      = logical & 15;                // o-group (fast)
    const int h       = logical >> 4;                // 0..61

    const int wv_i = threadIdx.x >> 6;               // wave 0..3
    const int o    = (og << 2) + wv_i;
    const int lane = threadIdx.x & 63;
    const int wg   = lane & 15;                      // w0 = 4*wg
    const int bg   = lane >> 4;                      // b0 = 8*bg
    const int w0   = wg * 4;
    const int b0   = bg * 8;
    const bool full = (wg < 15);                     // wg15 -> only w=60,61 stored

    float acc[8][4];
#pragma unroll
    for (int bi = 0; bi < 8; ++bi)
#pragma unroll
        for (int wi = 0; wi < 4; ++wi) acc[bi][wi] = 0.f;

    // W flat idx = o*(C*OH*OW*9) + c*(OH*OW*9) + h*(OW*9) + w*9 + i*3 + j
    const long wcstride = (long)OH_ * OW_ * 9;       // 34596
    const long wbase0   = (long)o * C_ * wcstride + (long)h * (OW_ * 9) + (long)w0 * 9;

    // x byte base for (b0, h, w0): b*524288 + h*256 + wg*16 (+c*16384, +bi*524288)
    const char* xb0 = (const char*)x + (unsigned)b0 * 524288u
                      + (unsigned)h * 256u + (unsigned)wg * 16u;

#define LOADW(arr, cidx) do {                                                   \
        const float* wp_ = Wt + wbase0 + (long)(cidx) * wcstride;               \
        _Pragma("unroll")                                                       \
        for (int q_ = 0; q_ < 18; ++q_) {                                       \
            if (q_ < 9 || full) {                                               \
                vfloat2 v_ = *reinterpret_cast<const vfloat2*>(wp_ + 2 * q_);   \
                arr[2 * q_] = v_.x; arr[2 * q_ + 1] = v_.y;                     \
            } else { arr[2 * q_] = 0.f; arr[2 * q_ + 1] = 0.f; }                \
        }                                                                       \
    } while (0)

    // 3 rows (float4 each) of batch b0+bi_, channel cidx: cols w0..w0+3
#define XROWS(dst, cidx, bi_) do {                                              \
        const char* p_ = xb0 + (unsigned)(bi_) * 524288u                        \
                         + (unsigned)(cidx) * 16384u;                           \
        dst[0] = *reinterpret_cast<const float4*>(p_);                          \
        dst[1] = *reinterpret_cast<const float4*>(p_ + 256);                    \
        dst[2] = *reinterpret_cast<const float4*>(p_ + 512);                    \
    } while (0)

    // expand 3x float4 -> 3x6 cols via DPP, then 36 FMAs into acc[bi_]
#define FMADPP(v4r, warr, bi_) do {                                             \
        float xr_[3][6];                                                        \
        _Pragma("unroll")                                                       \
        for (int r_ = 0; r_ < 3; ++r_) {                                        \
            xr_[r_][0] = v4r[r_].x; xr_[r_][1] = v4r[r_].y;                     \
            xr_[r_][2] = v4r[r_].z; xr_[r_][3] = v4r[r_].w;                     \
            xr_[r_][4] = dpp_nextlane(v4r[r_].x);                               \
            xr_[r_][5] = dpp_nextlane(v4r[r_].y);                               \
        }                                                                       \
        _Pragma("unroll")                                                       \
        for (int wi_ = 0; wi_ < 4; ++wi_)                                       \
        _Pragma("unroll")                                                       \
        for (int ii_ = 0; ii_ < 3; ++ii_)                                       \
        _Pragma("unroll")                                                       \
        for (int j_ = 0; j_ < 3; ++j_)                                          \
            acc[bi_][wi_] = fmaf(xr_[ii_][wi_ + j_],                            \
                                 warr[wi_ * 9 + ii_ * 3 + j_],                  \
                                 acc[bi_][wi_]);                                \
    } while (0)

    // one channel: software-pipelined over the 8 batches (static xA_/xB_)
#define COMPUTE(cidx, warr) do {                                                \
        float4 xA_[3], xB_[3];                                                  \
        XROWS(xA_, cidx, 0);                                                    \
        XROWS(xB_, cidx, 1); FMADPP(xA_, warr, 0);                              \
        XROWS(xA_, cidx, 2); FMADPP(xB_, warr, 1);                              \
        XROWS(xB_, cidx, 3); FMADPP(xA_, warr, 2);                              \
        XROWS(xA_, cidx, 4); FMADPP(xB_, warr, 3);                              \
        XROWS(xB_, cidx, 5); FMADPP(xA_, warr, 4);                              \
        XROWS(xA_, cidx, 6); FMADPP(xB_, warr, 5);                              \
        XROWS(xB_, cidx, 7); FMADPP(xA_, warr, 6);                              \
        FMADPP(xB_, warr, 7);                                                   \
    } while (0)

    float wvA[36], wvB[36];

    // ---- W pipeline: one channel ahead, no barriers anywhere
    LOADW(wvA, 0);
    for (int cc = 0; cc < C_; cc += 2) {
        LOADW(wvB, cc + 1);
        COMPUTE(cc, wvA);
        if (cc + 2 < C_) LOADW(wvA, cc + 2);
        COMPUTE(cc + 1, wvB);
    }

    // ---- epilogue: bias + nontemporal float2 stores (8B-aligned)
    const float* brow = bias + ((long)o * OH_ + h) * OW_ + w0;
    float2 bv0 = *reinterpret_cast<const float2*>(brow);
    float2 bv1;
    if (full) bv1 = *reinterpret_cast<const float2*>(brow + 2);
    else { bv1.x = 0.f; bv1.y = 0.f; }

#pragma unroll
    for (int bi = 0; bi < 8; ++bi) {
        float* orow = out + (((long)(b0 + bi) * O_ + o) * OH_ + h) * OW_ + w0;
        vfloat2 s0; s0.x = acc[bi][0] + bv0.x; s0.y = acc[bi][1] + bv0.y;
        __builtin_nontemporal_store(s0, reinterpret_cast<vfloat2*>(orow));
        if (full) {
            vfloat2 s1; s1.x = acc[bi][2] + bv1.x; s1.y = acc[bi][3] + bv1.y;
            __builtin_nontemporal_store(s1, reinterpret_cast<vfloat2*>(orow) + 1);
        }
    }

#undef LOADW
#undef XROWS
#undef FMADPP
#undef COMPUTE
}

extern "C" void kernel_launch(void* const* d_in, const int* in_sizes, int n_in,
                              void* d_out, int out_size, void* d_ws, size_t ws_size,
                              hipStream_t stream) {
    const float* x    = (const float*)d_in[0];
    const float* Wt   = (const float*)d_in[1];
    const float* bias = (const float*)d_in[2];
    float* out        = (float*)d_out;

    dim3 grid((O_ / 4) * OH_);   // 992 blocks, XCD-swizzled in-kernel
    dim3 block(256);
    lcl_kernel<<<grid, block, 0, stream>>>(x, Wt, bias, out);
}

// Round 10
// 186.376 us; speedup vs baseline: 7.4758x; 1.8960x over previous
//
#include <hip/hip_runtime.h>

// Locally connected layer:
// out[b,o,h,w] = sum_{c,i,j} x[b,c,h+i,w+j] * W[o,c,h,w,i,j] + bias[o,h,w]
// x: [32,32,64,64] f32, W: [64,32,62,62,3,3] f32, bias: [64,62,62] f32
// out: [32,64,62,62] f32
//
// R10: fix the two real walls found in R9's arithmetic:
//  (1) W loads were 144B-lane-strided (16 lines per instr -> TA-bound,
//      ~1500 cy/CU/channel). Now: wave stages its contiguous 2232-B W row
//      into LDS via 9 coalesced dword global_load_lds (per-wave private row,
//      NO barriers), lanes ds_read_b128 their 36 floats (144B lane stride =
//      2-way bank alias = free per m136).
//  (2) vmcnt retires IN ORDER: any load issued before x chains x-waits
//      behind 900-cy HBM. Order per channel: ds_read W(c) | x(c) 24xfloat4
//      (oldest VMEM) | gll-W(c+1) (youngest, stays in flight) | 288 FMAs.
//      Pinned with sched_barrier(0).
//  - DPP halo (0x101) validated R8. Chunked XCD swizzle kept. Plain
//    __launch_bounds__(256) (min-waves clause spilled in R4/R8 - never).

#define C_  32
#define B_  32
#define O_  64
#define H_  64
#define W_  64
#define OH_ 62
#define OW_ 62

typedef float vfloat2 __attribute__((ext_vector_type(2)));
typedef float vfloat4 __attribute__((ext_vector_type(4)));

#define GLL4(gaddr, laddr)                                                      \
    __builtin_amdgcn_global_load_lds(                                           \
        (const __attribute__((address_space(1))) void*)(gaddr),                 \
        (__attribute__((address_space(3))) void*)(laddr), 4, 0, 0)

// dst[lane] = src[lane+1] within each 16-lane row (validated R8)
__device__ __forceinline__ float dpp_nextlane(float v) {
    return __int_as_float(__builtin_amdgcn_update_dpp(
        0, __float_as_int(v), 0x101, 0xf, 0xf, true));
}

__global__ __launch_bounds__(256)
void lcl_kernel(const float* __restrict__ x,
                const float* __restrict__ Wt,
                const float* __restrict__ bias,
                float* __restrict__ out) {
    // Per-wave private W row, double-buffered: 2232 B used, 2304 B padded.
    __shared__ float ldsW[2][4][576];

    // ---- chunked XCD swizzle (hw: XCD = blockIdx.x % 8)
    const int nblk    = (O_ / 4) * OH_;              // 992 = 8 * 124
    const int i0      = blockIdx.x;
    const int logical = (i0 & 7) * (nblk >> 3) + (i0 >> 3);
    const int og      = logical & 15;                // o-group (fast)
    const int h       = logical >> 4;                // 0..61

    const int wv_i = threadIdx.x >> 6;               // wave 0..3
    const int o    = (og << 2) + wv_i;
    const int lane = threadIdx.x & 63;
    const int wg   = lane & 15;                      // w0 = 4*wg
    const int bg   = lane >> 4;                      // b0 = 8*bg
    const int w0   = wg * 4;
    const int b0   = bg * 8;
    const bool full = (wg < 15);                     // wg15 stores only w=60,61

    float acc[8][4];
#pragma unroll
    for (int bi = 0; bi < 8; ++bi)
#pragma unroll
        for (int wi = 0; wi < 4; ++wi) acc[bi][wi] = 0.f;

    // W row base (floats): o*C*34596 + h*558 (+ c*34596 per channel)
    const long wrowbase = (long)o * (C_ * 34596) + (long)h * 558;

    // x byte base for (b0, h, w0)
    const char* xb0 = (const char*)x + (unsigned)b0 * 524288u
                      + (unsigned)h * 256u + (unsigned)wg * 16u;

    // stage one 2232-B W row coalesced into this wave's LDS slot.
    // k=0..7: bytes [256k, 256k+256); k=8: bytes [1976, 2232) (clamped tail:
    // avoids reading past the very end of W; [1976,2048) double-written same).
#define STAGE_W(buf, cidx) do {                                                 \
        const char* src_ = (const char*)(Wt + wrowbase + (long)(cidx) * 34596); \
        char* dst_ = (char*)&ldsW[buf][wv_i][0];                                \
        _Pragma("unroll")                                                       \
        for (int k_ = 0; k_ < 8; ++k_)                                          \
            GLL4(src_ + k_ * 256 + lane * 4, dst_ + k_ * 256);                  \
        GLL4(src_ + 1976 + lane * 4, dst_ + 1976);                              \
    } while (0)

    // lane reads its 36 W floats (9 x b128, 144B lane stride = 2-way alias).
    // wg=15 reads 18 pad floats (garbage) -> only feeds acc[..][2/3], never
    // stored for that lane.
#define LOADW_LDS(buf) do {                                                     \
        const char* wrow_ = (const char*)&ldsW[buf][wv_i][0] + wg * 144;        \
        _Pragma("unroll")                                                       \
        for (int q_ = 0; q_ < 9; ++q_)                                          \
            wq[q_] = *reinterpret_cast<const vfloat4*>(wrow_ + q_ * 16);        \
    } while (0)

#define WQ(t) (wq[(t) >> 2][(t) & 3])

#define XLOADALL(cidx) do {                                                     \
        _Pragma("unroll")                                                       \
        for (int bi_ = 0; bi_ < 8; ++bi_) {                                     \
            const char* p_ = xb0 + (unsigned)bi_ * 524288u                      \
                             + (unsigned)(cidx) * 16384u;                       \
            xv[bi_][0] = *reinterpret_cast<const float4*>(p_);                  \
            xv[bi_][1] = *reinterpret_cast<const float4*>(p_ + 256);            \
            xv[bi_][2] = *reinterpret_cast<const float4*>(p_ + 512);            \
        }                                                                       \
    } while (0)

#define FMAALL() do {                                                           \
        _Pragma("unroll")                                                       \
        for (int bi_ = 0; bi_ < 8; ++bi_) {                                     \
            float xr_[3][6];                                                    \
            _Pragma("unroll")                                                   \
            for (int r_ = 0; r_ < 3; ++r_) {                                    \
                xr_[r_][0] = xv[bi_][r_].x; xr_[r_][1] = xv[bi_][r_].y;         \
                xr_[r_][2] = xv[bi_][r_].z; xr_[r_][3] = xv[bi_][r_].w;         \
                xr_[r_][4] = dpp_nextlane(xv[bi_][r_].x);                       \
                xr_[r_][5] = dpp_nextlane(xv[bi_][r_].y);                       \
            }                                                                   \
            _Pragma("unroll")                                                   \
            for (int wi_ = 0; wi_ < 4; ++wi_)                                   \
            _Pragma("unroll")                                                   \
            for (int ii_ = 0; ii_ < 3; ++ii_)                                   \
            _Pragma("unroll")                                                   \
            for (int j_ = 0; j_ < 3; ++j_)                                      \
                acc[bi_][wi_] = fmaf(xr_[ii_][wi_ + j_],                        \
                                     WQ(wi_ * 9 + ii_ * 3 + j_),                \
                                     acc[bi_][wi_]);                            \
        }                                                                       \
    } while (0)

    vfloat4 wq[9];
    float4  xv[8][3];

    // ---- prologue: stage W(0)
    STAGE_W(0, 0);

    for (int c = 0; c < C_; ++c) {
        // gll(c) is the only outstanding VMEM here (x(c-1) was older and
        // retired during FMAs). Wait for it, then read the row.
        asm volatile("s_waitcnt vmcnt(0)" ::: "memory");
        __builtin_amdgcn_sched_barrier(0);
        LOADW_LDS(c & 1);                 // 9 ds_read_b128 (lgkmcnt)
        XLOADALL(c);                      // 24 float4, OLDEST vmem of this c
        __builtin_amdgcn_sched_barrier(0);
        if (c + 1 < C_) STAGE_W((c + 1) & 1, c + 1);   // youngest, in flight
        __builtin_amdgcn_sched_barrier(0);
        FMAALL();                         // waits x only; gll streams under it
    }

    // ---- epilogue: bias + nontemporal float2 stores (8B-aligned)
    const float* brow = bias + ((long)o * OH_ + h) * OW_ + w0;
    float2 bv0 = *reinterpret_cast<const float2*>(brow);
    float2 bv1;
    if (full) bv1 = *reinterpret_cast<const float2*>(brow + 2);
    else { bv1.x = 0.f; bv1.y = 0.f; }

#pragma unroll
    for (int bi = 0; bi < 8; ++bi) {
        float* orow = out + (((long)(b0 + bi) * O_ + o) * OH_ + h) * OW_ + w0;
        vfloat2 s0; s0.x = acc[bi][0] + bv0.x; s0.y = acc[bi][1] + bv0.y;
        __builtin_nontemporal_store(s0, reinterpret_cast<vfloat2*>(orow));
        if (full) {
            vfloat2 s1; s1.x = acc[bi][2] + bv1.x; s1.y = acc[bi][3] + bv1.y;
            __builtin_nontemporal_store(s1, reinterpret_cast<vfloat2*>(orow) + 1);
        }
    }

#undef STAGE_W
#undef LOADW_LDS
#undef WQ
#undef XLOADALL
#undef FMAALL
}

extern "C" void kernel_launch(void* const* d_in, const int* in_sizes, int n_in,
                              void* d_out, int out_size, void* d_ws, size_t ws_size,
                              hipStream_t stream) {
    const float* x    = (const float*)d_in[0];
    const float* Wt   = (const float*)d_in[1];
    const float* bias = (const float*)d_in[2];
    float* out        = (float*)d_out;

    dim3 grid((O_ / 4) * OH_);   // 992 blocks, XCD-swizzled in-kernel
    dim3 block(256);
    lcl_kernel<<<grid, block, 0, stream>>>(x, Wt, bias, out);
}